// Round 11
// baseline (90.953 us; speedup 1.0000x reference)
//
#include <hip/hip_runtime.h>
#include <hip/hip_bf16.h>

// y[b,i,j] = s[b,i] + s[b,j] - 2 * sum_k U[b,i,k]*U[b,j,k],  U = bf16(g^t * V)
//   (w*Vi*Vj = (g^t Vi)(g^t Vj), w = max(G,0)^(2t))  s[b,i] = sum_k U[b,i,k]^2
// bs=4, r=4096, d=64. Output 268 MB fp32 -> write-bandwidth bound.
// R10 -> R11: revert persistence (regressed). NEW: short-i/long-j block
// tile 16x1024 so each wave's store stream is 4KB-sequential runs
// (was 1KB runs @ 16KB stride -> DRAM page thrash theory). 8 waves of
// 16x128 (acc 32 VGPR -> ~95 total, 2 blocks/CU kept). LDS stages
// 8x1024 per chunk (32.9 KB); wave w stores row w = 4 consecutive 1KB
// instrs. NT stores + lgkm-only barriers + j-fastest grid kept from R9.

typedef __attribute__((ext_vector_type(8))) short bf16x8;   // 8 bf16 = 4 VGPRs
typedef __attribute__((ext_vector_type(4))) float f32x4;

constexpr int BS = 4, R = 4096, D = 64;
constexpr int BN  = 1024;        // block j extent
constexpr int LSW = BN + 4;      // LDS row stride (floats), 16B-aligned pad

__device__ __forceinline__ void barrier_lds_only() {
    // order LDS ops, but let global (NT) stores stay in flight
    asm volatile("s_waitcnt lgkmcnt(0)" ::: "memory");
    __builtin_amdgcn_sched_barrier(0);
    __builtin_amdgcn_s_barrier();
    __builtin_amdgcn_sched_barrier(0);
}

// ---------------------------------------------------------------- prep ------
// One wave per row (64 lanes == d). Emits U = bf16(g^t * V), fp32 s = sum U^2.
__global__ __launch_bounds__(256) void prep_kernel(
    const float* __restrict__ G, const float* __restrict__ V,
    const float* __restrict__ wt,
    __hip_bfloat16* __restrict__ u_bf, float* __restrict__ s)
{
    int row  = blockIdx.x * 4 + (threadIdx.x >> 6);   // global row in [0, BS*R)
    int lane = threadIdx.x & 63;                       // k index (d == 64)
    if (row >= BS * R) return;
    int b = row / R;

    float t  = wt[0];
    float g  = fmaxf(G[b * D + lane], 0.0f);
    float sw = powf(g, t);                             // g^t; 0^0==1 matches jnp
    float u  = sw * V[(size_t)row * D + lane];

    __hip_bfloat16 ub = __float2bfloat16(u);
    u_bf[(size_t)row * D + lane] = ub;

    // s from the same bf16-rounded values -> diagonal cancels vs MFMA cross
    float uf   = __bfloat162float(ub);
    float prod = uf * uf;
    #pragma unroll
    for (int off = 32; off; off >>= 1) prod += __shfl_down(prod, off);
    if (lane == 0) s[row] = prod;
}

// ---------------------------------------------------------------- dist ------
// Block: 512 threads = 8 waves arranged 1 (i) x 8 (j); wave tile 16x128.
// Block tile 16 (i) x 1024 (j). Grid: (R/1024 j [FAST], R/16 i, BS).
// MFMA 16x16x32 bf16 layouts (HW-verified, learn_hip m89/m91/m97):
//   A: lane holds A[row=l&15][k=(l>>4)*8 + 0..7]   (contiguous 16B)
//   B: lane holds B[k=(l>>4)*8 + 0..7][col=l&15] == U[j+(l&15)][k...] for B=U^T
//   C/D: col = l&15, row = (l>>4)*4 + reg
// Epilogue: 2 chunks of 8 rows: y -> LDS[8][1028] -> wave w stores row w
// as 4 consecutive 1KB instructions (4KB sequential run per wave).
__global__ __launch_bounds__(512) void dist_kernel(
    const short* __restrict__ U, const float* __restrict__ s,
    float* __restrict__ out)
{
    __shared__ float lds[8 * LSW];   // 32.9 KB -> LDS allows 4 blocks/CU; VGPR gives 2

    int lane = threadIdx.x & 63;
    int wave = threadIdx.x >> 6;     // 0..7  (j position)
    int lrow = lane & 15;
    int kgrp = lane >> 4;            // 0..3

    int b  = blockIdx.z;
    int jb = blockIdx.x * BN;        // FAST axis: j -> contiguous write window
    int i0 = blockIdx.y * 16;
    int jw = wave * 128;             // wave's j offset within block

    const short* Ap = U + ((size_t)b * R + i0) * D;        // 16 rows
    const short* Bp = U + ((size_t)b * R + jb + jw) * D;   // 128 rows
    const float* sb = s + (size_t)b * R;

    // A fragments (single 16-row block x 2 K-steps)
    bf16x8 a0 = *(const bf16x8*)(Ap + lrow * D +      kgrp * 8);
    bf16x8 a1 = *(const bf16x8*)(Ap + lrow * D + 32 + kgrp * 8);

    f32x4 acc[8];
    #pragma unroll
    for (int jt = 0; jt < 8; ++jt) acc[jt] = f32x4{0.f, 0.f, 0.f, 0.f};

    #pragma unroll
    for (int jt = 0; jt < 8; ++jt) {
        const short* Bt = Bp + jt * 16 * D;
        bf16x8 b0 = *(const bf16x8*)(Bt + lrow * D +      kgrp * 8);
        bf16x8 b1 = *(const bf16x8*)(Bt + lrow * D + 32 + kgrp * 8);
        acc[jt] = __builtin_amdgcn_mfma_f32_16x16x32_bf16(a0, b0, acc[jt], 0, 0, 0);
        acc[jt] = __builtin_amdgcn_mfma_f32_16x16x32_bf16(a1, b1, acc[jt], 0, 0, 0);
    }

    // row sums: lane's 4 output rows are kgrp*4+rg (rg=0..3), all in chunk kgrp>>1
    float si_lane = sb[i0 + (lane & 15)];
    float si[4];
    #pragma unroll
    for (int rg = 0; rg < 4; ++rg) si[rg] = __shfl(si_lane, kgrp * 4 + rg);
    float sj[8];
    #pragma unroll
    for (int jt = 0; jt < 8; ++jt) sj[jt] = sb[jb + jw + jt * 16 + lrow];

    float* outb = out + ((size_t)b * R + i0) * R + jb;

    #pragma unroll
    for (int c = 0; c < 2; ++c) {
        // chunk c covers rows c*8 .. c*8+7; lane participates iff kgrp>>1 == c
        if ((kgrp >> 1) == c) {
            int lr4 = (kgrp & 1) * 4;                  // local row base 0 or 4
            #pragma unroll
            for (int rg = 0; rg < 4; ++rg) {
                #pragma unroll
                for (int jt = 0; jt < 8; ++jt) {
                    float y = si[rg] + sj[jt] - 2.0f * acc[jt][rg];
                    lds[(lr4 + rg) * LSW + jw + jt * 16 + lrow] = y;
                }
            }
        }
        barrier_lds_only();   // ds_writes visible; global stores NOT drained

        // wave w stores chunk row w: 4 consecutive 1KB segments = 4KB run
        #pragma unroll
        for (int t = 0; t < 4; ++t) {
            f32x4 v = *(const f32x4*)&lds[wave * LSW + t * 256 + lane * 4];
            __builtin_nontemporal_store(v,
                (f32x4*)(outb + (size_t)(c * 8 + wave) * R + t * 256 + lane * 4));
        }
        if (c == 0) barrier_lds_only();   // ds_reads done -> chunk-1 may overwrite
    }
}

// --------------------------------------------------------------------------
extern "C" void kernel_launch(void* const* d_in, const int* in_sizes, int n_in,
                              void* d_out, int out_size, void* d_ws, size_t ws_size,
                              hipStream_t stream) {
    const float* G  = (const float*)d_in[0];
    const float* V  = (const float*)d_in[1];
    const float* wt = (const float*)d_in[2];
    float* out = (float*)d_out;

    char* ws = (char*)d_ws;
    __hip_bfloat16* u_bf = (__hip_bfloat16*)ws;                             // 2 MB
    float*          s    = (float*)        (ws + (size_t)BS * R * D * 2);   // 64 KB

    prep_kernel<<<BS * R / 4, 256, 0, stream>>>(G, V, wt, u_bf, s);

    dim3 grid(R / BN, R / 16, BS);   // j fastest -> contiguous write window
    dist_kernel<<<grid, 512, 0, stream>>>((const short*)u_bf, s, out);
}

// Round 12
// 77.647 us; speedup vs baseline: 1.1714x; 1.1714x over previous
//
#include <hip/hip_runtime.h>
#include <hip/hip_bf16.h>

// y[b,i,j] = s[b,i] + s[b,j] - 2 * sum_k U[b,i,k]*U[b,j,k],  U = bf16(g^t * V)
//   (w*Vi*Vj = (g^t Vi)(g^t Vj), w = max(G,0)^(2t))  s[b,i] = sum_k U[b,i,k]^2
// bs=4, r=4096, d=64. Output 268 MB fp32 -> write-bandwidth bound.
// R11 -> R12: revert 16x1024 (read-amp confounded). NEW: 32x32x16 MFMA so
// the C/D layout itself yields full-line stores (col=lane&31 -> lanes 0-31
// = one 128B line, lanes 32-63 = second line, per reg). Epilogue LDS
// round-trip (64 ds_write + 16 ds_read/wave) and ALL barriers eliminated;
// waves independent -> store issue spread in time, not bursty.
// Block 128x256 (8 waves 4i x 2j, wave 32x128), grid j-fastest, NT stores.

typedef __attribute__((ext_vector_type(8)))  short bf16x8;   // 8 bf16 = 4 VGPRs
typedef __attribute__((ext_vector_type(16))) float f32x16;

constexpr int BS = 4, R = 4096, D = 64;

// ---------------------------------------------------------------- prep ------
// One wave per row (64 lanes == d). Emits U = bf16(g^t * V), fp32 s = sum U^2.
__global__ __launch_bounds__(256) void prep_kernel(
    const float* __restrict__ G, const float* __restrict__ V,
    const float* __restrict__ wt,
    __hip_bfloat16* __restrict__ u_bf, float* __restrict__ s)
{
    int row  = blockIdx.x * 4 + (threadIdx.x >> 6);   // global row in [0, BS*R)
    int lane = threadIdx.x & 63;                       // k index (d == 64)
    if (row >= BS * R) return;
    int b = row / R;

    float t  = wt[0];
    float g  = fmaxf(G[b * D + lane], 0.0f);
    float sw = powf(g, t);                             // g^t; 0^0==1 matches jnp
    float u  = sw * V[(size_t)row * D + lane];

    __hip_bfloat16 ub = __float2bfloat16(u);
    u_bf[(size_t)row * D + lane] = ub;

    // s from the same bf16-rounded values -> diagonal cancels vs MFMA cross
    float uf   = __bfloat162float(ub);
    float prod = uf * uf;
    #pragma unroll
    for (int off = 32; off; off >>= 1) prod += __shfl_down(prod, off);
    if (lane == 0) s[row] = prod;
}

// ---------------------------------------------------------------- dist ------
// Block: 512 threads = 8 waves arranged 4 (i) x 2 (j); wave tile 32x128.
// Block tile 128 (i) x 256 (j). Grid: (R/256 j [FAST], R/128 i, BS).
// MFMA 32x32x16 bf16 layouts:
//   A: lane holds A[row=l&31][k = ks*16 + (l>>5)*8 + 0..7]  (16B contiguous)
//   B: lane holds B[k...][col=l&31] == U[j+(l&31)][k...] for B=U^T
//   C/D (HW-verified m74/m101): col=l&31, row=(r&3)+8*(r>>2)+4*(l>>5)
// Store: one global_store_dword per reg = 2 full 128B lines. No LDS/barriers.
__global__ __launch_bounds__(512, 4) void dist_kernel(
    const short* __restrict__ U, const float* __restrict__ s,
    float* __restrict__ out)
{
    int lane = threadIdx.x & 63;
    int wave = threadIdx.x >> 6;     // 0..7
    int wr   = wave >> 1;            // 0..3  (i band of 32)
    int wc   = wave & 1;             // 0..1  (j half of 128)
    int half = lane >> 5;            // 0..1
    int l31  = lane & 31;

    int b  = blockIdx.z;
    int jb = blockIdx.x * 256;       // FAST axis: j -> contiguous write window
    int i0 = blockIdx.y * 128;
    int iw = i0 + wr * 32;
    int jw = jb + wc * 128;

    const short* Ap = U + ((size_t)b * R + iw) * D;   // 32 rows x 64
    const short* Bp = U + ((size_t)b * R + jw) * D;   // 128 rows x 64
    const float* sb = s + (size_t)b * R;

    // A fragments: 4 K-steps of 16
    bf16x8 a[4];
    #pragma unroll
    for (int ks = 0; ks < 4; ++ks)
        a[ks] = *(const bf16x8*)(Ap + l31 * D + ks * 16 + half * 8);

    f32x16 acc[4];
    #pragma unroll
    for (int jt = 0; jt < 4; ++jt)
        #pragma unroll
        for (int r = 0; r < 16; ++r) acc[jt][r] = 0.f;

    #pragma unroll
    for (int jt = 0; jt < 4; ++jt) {
        const short* Bt = Bp + jt * 32 * D;
        #pragma unroll
        for (int ks = 0; ks < 4; ++ks) {
            bf16x8 bq = *(const bf16x8*)(Bt + l31 * D + ks * 16 + half * 8);
            acc[jt] = __builtin_amdgcn_mfma_f32_32x32x16_bf16(a[ks], bq, acc[jt], 0, 0, 0);
        }
    }

    // epilogue: direct full-line stores from acc
    float si_lane = sb[iw + l31];            // lane c (c<32) holds s[iw+c]
    float* outb = out + ((size_t)b * R + iw) * R + jw;

    #pragma unroll
    for (int jt = 0; jt < 4; ++jt) {
        float sj = sb[jw + jt * 32 + l31];
        #pragma unroll
        for (int r = 0; r < 16; ++r) {
            int row  = (r & 3) + 8 * (r >> 2) + 4 * half;   // 0..31
            float si = __shfl(si_lane, row);
            float y  = si + sj - 2.0f * acc[jt][r];
            __builtin_nontemporal_store(y,
                outb + (size_t)row * R + jt * 32 + l31);
        }
    }
}

// --------------------------------------------------------------------------
extern "C" void kernel_launch(void* const* d_in, const int* in_sizes, int n_in,
                              void* d_out, int out_size, void* d_ws, size_t ws_size,
                              hipStream_t stream) {
    const float* G  = (const float*)d_in[0];
    const float* V  = (const float*)d_in[1];
    const float* wt = (const float*)d_in[2];
    float* out = (float*)d_out;

    char* ws = (char*)d_ws;
    __hip_bfloat16* u_bf = (__hip_bfloat16*)ws;                             // 2 MB
    float*          s    = (float*)        (ws + (size_t)BS * R * D * 2);   // 64 KB

    prep_kernel<<<BS * R / 4, 256, 0, stream>>>(G, V, wt, u_bf, s);

    dim3 grid(R / 256, R / 128, BS);   // j fastest -> contiguous write window
    dist_kernel<<<grid, 512, 0, stream>>>((const short*)u_bf, s, out);
}

// Round 13
// 66.017 us; speedup vs baseline: 1.3777x; 1.1762x over previous
//
#include <hip/hip_runtime.h>
#include <hip/hip_bf16.h>

// y[b,i,j] = s[b,i] + s[b,j] - 2 * sum_k U[b,i,k]*U[b,j,k],  U = bf16(g^t * V)
//   (w*Vi*Vj = (g^t Vi)(g^t Vj), w = max(G,0)^(2t))  s[b,i] = sum_k U[b,i,k]^2
// bs=4, r=4096, d=64. Output 268 MB fp32 -> write-bandwidth bound.
// R12 -> R13: revert to R9 structure (LDS-staged dwordx4 epilogue was best;
// direct scalar stores regressed). SINGLE LEVER: 4 chunks of 32 rows ->
// LDS 33.3 KB + __launch_bounds__(512,3) -> 3 blocks/CU (was 2) for more
// decorrelated store streams per CU (store-pipe smoothing).

typedef __attribute__((ext_vector_type(8))) short bf16x8;   // 8 bf16 = 4 VGPRs
typedef __attribute__((ext_vector_type(4))) float f32x4;

constexpr int BS = 4, R = 4096, D = 64;
constexpr int LS = 260;   // LDS row stride (floats): 16B-aligned rows, 2-way max conflict (free)

__device__ __forceinline__ void barrier_lds_only() {
    // order LDS ops, but let global (NT) stores stay in flight
    asm volatile("s_waitcnt lgkmcnt(0)" ::: "memory");
    __builtin_amdgcn_sched_barrier(0);
    __builtin_amdgcn_s_barrier();
    __builtin_amdgcn_sched_barrier(0);
}

// ---------------------------------------------------------------- prep ------
// One wave per row (64 lanes == d). Emits U = bf16(g^t * V), fp32 s = sum U^2.
__global__ __launch_bounds__(256) void prep_kernel(
    const float* __restrict__ G, const float* __restrict__ V,
    const float* __restrict__ wt,
    __hip_bfloat16* __restrict__ u_bf, float* __restrict__ s)
{
    int row  = blockIdx.x * 4 + (threadIdx.x >> 6);   // global row in [0, BS*R)
    int lane = threadIdx.x & 63;                       // k index (d == 64)
    if (row >= BS * R) return;
    int b = row / R;

    float t  = wt[0];
    float g  = fmaxf(G[b * D + lane], 0.0f);
    float sw = powf(g, t);                             // g^t; 0^0==1 matches jnp
    float u  = sw * V[(size_t)row * D + lane];

    __hip_bfloat16 ub = __float2bfloat16(u);
    u_bf[(size_t)row * D + lane] = ub;

    // s from the same bf16-rounded values -> diagonal cancels vs MFMA cross
    float uf   = __bfloat162float(ub);
    float prod = uf * uf;
    #pragma unroll
    for (int off = 32; off; off >>= 1) prod += __shfl_down(prod, off);
    if (lane == 0) s[row] = prod;
}

// ---------------------------------------------------------------- dist ------
// Block: 512 threads = 8 waves, arranged 2 (i) x 4 (j); wave tile 64x64.
// Block tile 128 (i) x 256 (j). Grid: (R/256 j [FAST], R/128 i, BS).
// MFMA 16x16x32 bf16 layouts (HW-verified, learn_hip m89/m91/m97):
//   A: lane holds A[row=l&15][k=(l>>4)*8 + 0..7]   (contiguous 16B)
//   B: lane holds B[k=(l>>4)*8 + 0..7][col=l&15] == U[j0+(l&15)][k...] for B=U^T
//   C/D: col = l&15, row = (l>>4)*4 + reg
// Epilogue: FOUR 32-row chunks: y -> LDS[32][260] -> full-row 1KB NT stores.
__global__ __launch_bounds__(512, 3) void dist_kernel(
    const short* __restrict__ U, const float* __restrict__ s,
    float* __restrict__ out)
{
    __shared__ float lds[32 * LS];   // 33.3 KB -> 3 blocks/CU (VGPR-capped)

    int lane = threadIdx.x & 63;
    int wave = threadIdx.x >> 6;     // 0..7
    int wr   = wave >> 2;            // 0..1  (i half)
    int wc   = wave & 3;             // 0..3  (j quarter)

    int b  = blockIdx.z;
    int jb = blockIdx.x * 256;       // FAST axis: j -> contiguous write window
    int i0 = blockIdx.y * 128;

    const short* Ap = U + ((size_t)b * R + i0 + wr * 64) * D;   // 64 rows
    const short* Bp = U + ((size_t)b * R + jb + wc * 64) * D;   // 64 rows
    const float* sb = s + (size_t)b * R;

    int lrow = lane & 15;
    int kgrp = lane >> 4;            // 0..3

    // A fragments: 4 row-blocks x 2 K-steps
    bf16x8 a[4][2];
    #pragma unroll
    for (int rb = 0; rb < 4; ++rb)
        #pragma unroll
        for (int ks = 0; ks < 2; ++ks)
            a[rb][ks] = *(const bf16x8*)(Ap + (rb * 16 + lrow) * D + ks * 32 + kgrp * 8);

    f32x4 acc[4][4];
    #pragma unroll
    for (int rb = 0; rb < 4; ++rb)
        #pragma unroll
        for (int jt = 0; jt < 4; ++jt)
            acc[rb][jt] = f32x4{0.f, 0.f, 0.f, 0.f};

    #pragma unroll
    for (int jt = 0; jt < 4; ++jt) {
        const short* Bt = Bp + jt * 16 * D;
        bf16x8 b0 = *(const bf16x8*)(Bt + lrow * D +      kgrp * 8);
        bf16x8 b1 = *(const bf16x8*)(Bt + lrow * D + 32 + kgrp * 8);
        #pragma unroll
        for (int rb = 0; rb < 4; ++rb) {
            acc[rb][jt] = __builtin_amdgcn_mfma_f32_16x16x32_bf16(a[rb][0], b0, acc[rb][jt], 0, 0, 0);
            acc[rb][jt] = __builtin_amdgcn_mfma_f32_16x16x32_bf16(a[rb][1], b1, acc[rb][jt], 0, 0, 0);
        }
    }

    // per-lane row sums for this wave's 64 rows
    float si_lane = sb[i0 + wr * 64 + lane];

    float* outb = out + ((size_t)b * R + i0) * R + jb;

    #pragma unroll
    for (int c = 0; c < 4; ++c) {
        // chunk c covers block rows c*32 .. c*32+31; writers: waves wr == c>>1,
        // using their rb in {(c&1)*2, (c&1)*2+1}.
        if (wr == (c >> 1)) {
            #pragma unroll
            for (int rb2 = 0; rb2 < 2; ++rb2) {
                int rb = (c & 1) * 2 + rb2;
                #pragma unroll
                for (int rg = 0; rg < 4; ++rg) {
                    int rl = rb * 16 + kgrp * 4 + rg;      // 0..63 within wave
                    int rc = rl - (c & 1) * 32;            // 0..31 within chunk
                    float si = __shfl(si_lane, rl);
                    #pragma unroll
                    for (int jt = 0; jt < 4; ++jt) {
                        float sj = sb[jb + wc * 64 + jt * 16 + lrow];
                        float y  = si + sj - 2.0f * acc[rb][jt][rg];
                        lds[rc * LS + wc * 64 + jt * 16 + lrow] = y;
                    }
                }
            }
        }
        barrier_lds_only();   // ds_writes visible; global stores NOT drained

        // all 8 waves store chunk c: wave w -> rows w*4..w*4+3 of the chunk.
        // Each instruction: 64 lanes x 16B = one contiguous 1KB segment.
        #pragma unroll
        for (int r = 0; r < 4; ++r) {
            int rl = wave * 4 + r;
            f32x4 v = *(const f32x4*)&lds[rl * LS + lane * 4];
            __builtin_nontemporal_store(v,
                (f32x4*)(outb + (size_t)(c * 32 + rl) * R + lane * 4));
        }
        if (c < 3) barrier_lds_only();   // ds_reads done -> next chunk may overwrite
    }
}

// --------------------------------------------------------------------------
extern "C" void kernel_launch(void* const* d_in, const int* in_sizes, int n_in,
                              void* d_out, int out_size, void* d_ws, size_t ws_size,
                              hipStream_t stream) {
    const float* G  = (const float*)d_in[0];
    const float* V  = (const float*)d_in[1];
    const float* wt = (const float*)d_in[2];
    float* out = (float*)d_out;

    char* ws = (char*)d_ws;
    __hip_bfloat16* u_bf = (__hip_bfloat16*)ws;                             // 2 MB
    float*          s    = (float*)        (ws + (size_t)BS * R * D * 2);   // 64 KB

    prep_kernel<<<BS * R / 4, 256, 0, stream>>>(G, V, wt, u_bf, s);

    dim3 grid(R / 256, R / 128, BS);   // j fastest -> contiguous write window
    dist_kernel<<<grid, 512, 0, stream>>>((const short*)u_bf, s, out);
}